// Round 11
// baseline (1023.384 us; speedup 1.0000x reference)
//
#include <hip/hip_runtime.h>
#include <hip/hip_fp16.h>
#include <cstdint>

#define T_LEN 128
#define DA    16
#define DZ    32
#define HH    128

__device__ __forceinline__ float sigm(float x){ return 1.0f/(1.0f + __expf(-x)); }
__device__ __forceinline__ float tanh_f(float x){ return 1.0f - 2.0f/(__expf(2.0f*x)+1.0f); }

typedef _Float16 h2v __attribute__((ext_vector_type(2)));
__device__ __forceinline__ float fdot2(uint32_t w, uint32_t h, float acc){
  union{uint32_t u; h2v v;} a, b; a.u = w; b.u = h;
  return __builtin_amdgcn_fdot2(a.v, b.v, acc, false);
}
__device__ __forceinline__ uint32_t packh2(float x, float y){
  return (uint32_t)__half_as_ushort(__float2half(x)) |
         ((uint32_t)__half_as_ushort(__float2half(y)) << 16);
}
__device__ __forceinline__ float h2lo(uint32_t u){
  return __half2float(__ushort_as_half((unsigned short)(u & 0xffffu)));
}
__device__ __forceinline__ float h2hi(uint32_t u){
  return __half2float(__ushort_as_half((unsigned short)(u >> 16)));
}
__device__ __forceinline__ float dot8(uint4 a, uint4 b, float acc){
  acc = fdot2(a.x, b.x, acc); acc = fdot2(a.y, b.y, acc);
  acc = fdot2(a.z, b.z, acc); acc = fdot2(a.w, b.w, acc);
  return acc;
}
__device__ __forceinline__ float dot8f(uint4 h, float4 f0, float4 f1, float acc){
  acc += h2lo(h.x)*f0.x + h2hi(h.x)*f0.y + h2lo(h.y)*f0.z + h2hi(h.y)*f0.w;
  acc += h2lo(h.z)*f1.x + h2hi(h.z)*f1.y + h2lo(h.w)*f1.z + h2hi(h.w)*f1.w;
  return acc;
}

// LDS-only barrier: drain LDS pipe, raw s_barrier (no vmcnt drain).
#define BAR() do { asm volatile("s_waitcnt lgkmcnt(0)" ::: "memory"); \
                   __builtin_amdgcn_s_barrier(); } while (0)

__global__ void prep_kernel(const float* __restrict__ Wih0, const float* __restrict__ Whh0,
                            const float* __restrict__ bih0, const float* __restrict__ bhh0,
                            const float* __restrict__ Wih1, const float* __restrict__ Whh1,
                            const float* __restrict__ bih1, const float* __restrict__ bhh1,
                            uint32_t* __restrict__ ws) {
  int idx = blockIdx.x*256 + threadIdx.x;
  if (idx < 4096) {
    int q = idx & 3, g = (idx >> 2) & 511, m = idx >> 11;
    int k0 = 8*m + 2*q;
    ws[idx] = packh2(Wih0[g*DA + k0], Wih0[g*DA + k0 + 1]);
  } else if (idx < 36864) {
    int f = idx - 4096;
    int q = f & 3, g = (f >> 2) & 511, m = f >> 11;
    int k0 = 8*m + 2*q;
    ws[idx] = packh2(Whh0[g*HH + k0], Whh0[g*HH + k0 + 1]);
  } else if (idx < 69632) {
    int f = idx - 36864;
    int q = f & 3, g = (f >> 2) & 511, m = f >> 11;
    int k0 = 8*m + 2*q;
    ws[idx] = packh2(Wih1[g*HH + k0], Wih1[g*HH + k0 + 1]);
  } else if (idx < 102400) {
    int f = idx - 69632;
    int q = f & 3, g = (f >> 2) & 511, m = f >> 11;
    int k0 = 8*m + 2*q;
    ws[idx] = packh2(Whh1[g*HH + k0], Whh1[g*HH + k0 + 1]);
  } else if (idx < 102912) {
    int j = idx - 102400;
    ((float*)ws)[idx] = bih0[j] + bhh0[j];
  } else if (idx < 103424) {
    int j = idx - 102912;
    ((float*)ws)[idx] = bih1[j] + bhh1[j];
  }
}

// Persistent 2-layer LSTM (round-8 version, unchanged).
__global__ __launch_bounds__(512, 2) void lstm_kernel(
    const float* __restrict__ a, const float* __restrict__ a0,
    const uint32_t* __restrict__ wsw, const float* __restrict__ Wlin,
    const float* __restrict__ blin, float* __restrict__ alpha_out) {
  const uint4* Wih0p = (const uint4*)(wsw);
  const uint4* Whh0p = (const uint4*)(wsw + 4096);
  const uint4* Wih1p = (const uint4*)(wsw + 36864);
  const uint4* Whh1p = (const uint4*)(wsw + 69632);
  const float* b0v = (const float*)(wsw + 102400);
  const float* b1v = (const float*)(wsw + 102912);

  __shared__ __align__(16) uint32_t sxh[2][T_LEN][8];
  __shared__ __align__(16) uint32_t sh0h[2][64];
  __shared__ __align__(16) uint32_t sh1h[2][64];
  __shared__ float gates[2][4*HH];
  __shared__ float hpart[4][3];

  int tid = threadIdx.x;
  int lane = tid & 63;
  int wv = tid >> 6;
  int bb = blockIdx.x * 2;

  uint4 wi0[2], wh0[16], wi1[16], wh1[16];
  #pragma unroll
  for (int m = 0; m < 2; ++m)  wi0[m] = Wih0p[m*512 + tid];
  #pragma unroll
  for (int m = 0; m < 16; ++m) wh0[m] = Whh0p[m*512 + tid];
  #pragma unroll
  for (int m = 0; m < 16; ++m) wi1[m] = Wih1p[m*512 + tid];
  #pragma unroll
  for (int m = 0; m < 16; ++m) wh1[m] = Whh1p[m*512 + tid];
  float bi0 = b0v[tid], bi1 = b1v[tid];

  for (int i = tid; i < 2*T_LEN*8; i += 512) {
    int r = i / (T_LEN*8), rem = i % (T_LEN*8), t = rem >> 3, p = rem & 7;
    float x0, x1;
    if (t == 0) { x0 = a0[2*p]; x1 = a0[2*p+1]; }
    else {
      const float* src = a + ((size_t)(bb + r)*T_LEN + (t-1))*DA;
      x0 = src[2*p]; x1 = src[2*p+1];
    }
    sxh[r][t][p] = packh2(x0, x1);
  }
  float wl0 = Wlin[0*HH + (tid & 127)];
  float wl1 = Wlin[1*HH + (tid & 127)];
  float wl2 = Wlin[2*HH + (tid & 127)];
  float bl0 = blin[0], bl1 = blin[1], bl2 = blin[2];
  float cl0 = 0.f, cl1 = 0.f;
  if (tid < 128) { sh0h[wv][lane] = 0u; sh1h[wv][lane] = 0u; }
  __syncthreads();

  #pragma unroll 1
  for (int t = 0; t < T_LEN; ++t) {
    {
      float g0a = bi0, g0b = 0.f, g1a = bi0, g1b = 0.f;
      uint4 xA0 = *(const uint4*)&sxh[0][t][0];
      uint4 xA1 = *(const uint4*)&sxh[0][t][4];
      uint4 xB0 = *(const uint4*)&sxh[1][t][0];
      uint4 xB1 = *(const uint4*)&sxh[1][t][4];
      g0a = fdot2(wi0[0].x, xA0.x, g0a); g0b = fdot2(wi0[0].y, xA0.y, g0b);
      g0a = fdot2(wi0[0].z, xA0.z, g0a); g0b = fdot2(wi0[0].w, xA0.w, g0b);
      g0a = fdot2(wi0[1].x, xA1.x, g0a); g0b = fdot2(wi0[1].y, xA1.y, g0b);
      g0a = fdot2(wi0[1].z, xA1.z, g0a); g0b = fdot2(wi0[1].w, xA1.w, g0b);
      g1a = fdot2(wi0[0].x, xB0.x, g1a); g1b = fdot2(wi0[0].y, xB0.y, g1b);
      g1a = fdot2(wi0[0].z, xB0.z, g1a); g1b = fdot2(wi0[0].w, xB0.w, g1b);
      g1a = fdot2(wi0[1].x, xB1.x, g1a); g1b = fdot2(wi0[1].y, xB1.y, g1b);
      g1a = fdot2(wi0[1].z, xB1.z, g1a); g1b = fdot2(wi0[1].w, xB1.w, g1b);
      #pragma unroll
      for (int m = 0; m < 16; ++m) {
        uint4 w = wh0[m];
        uint4 hA = *(const uint4*)&sh0h[0][4*m];
        uint4 hB = *(const uint4*)&sh0h[1][4*m];
        g0a = fdot2(w.x, hA.x, g0a); g0b = fdot2(w.y, hA.y, g0b);
        g0a = fdot2(w.z, hA.z, g0a); g0b = fdot2(w.w, hA.w, g0b);
        g1a = fdot2(w.x, hB.x, g1a); g1b = fdot2(w.y, hB.y, g1b);
        g1a = fdot2(w.z, hB.z, g1a); g1b = fdot2(w.w, hB.w, g1b);
      }
      gates[0][tid] = g0a + g0b;
      gates[1][tid] = g1a + g1b;
    }
    __syncthreads();                                   // B1
    if (t > 0 && tid >= 504 && tid < 506) {
      int row = tid - 504;
      float l0 = hpart[2*row][0] + hpart[2*row+1][0] + bl0;
      float l1 = hpart[2*row][1] + hpart[2*row+1][1] + bl1;
      float l2 = hpart[2*row][2] + hpart[2*row+1][2] + bl2;
      float mx = fmaxf(l0, fmaxf(l1, l2));
      float e0=__expf(l0-mx), e1=__expf(l1-mx), e2=__expf(l2-mx);
      float inv = 1.0f/(e0+e1+e2);
      float* dst = alpha_out + (((size_t)(bb+row))*T_LEN + (t-1))*3;
      dst[0]=e0*inv; dst[1]=e1*inv; dst[2]=e2*inv;
    }
    if (tid < 256) {
      int row = tid >> 7, cell = tid & 127;
      float iv = gates[row][cell],      fv = gates[row][cell+HH],
            qv = gates[row][cell+2*HH], ov = gates[row][cell+3*HH];
      cl0 = sigm(fv)*cl0 + sigm(iv)*tanh_f(qv);
      float hv = sigm(ov)*tanh_f(cl0);
      ((__half*)&sh0h[0][0])[row*128 + cell] = __float2half(hv);
    }
    __syncthreads();                                   // B2
    {
      float g0a = bi1, g0b = 0.f, g1a = bi1, g1b = 0.f;
      #pragma unroll
      for (int m = 0; m < 16; ++m) {
        uint4 w = wi1[m];
        uint4 hA = *(const uint4*)&sh0h[0][4*m];
        uint4 hB = *(const uint4*)&sh0h[1][4*m];
        g0a = fdot2(w.x, hA.x, g0a); g0b = fdot2(w.y, hA.y, g0b);
        g0a = fdot2(w.z, hA.z, g0a); g0b = fdot2(w.w, hA.w, g0b);
        g1a = fdot2(w.x, hB.x, g1a); g1b = fdot2(w.y, hB.y, g1b);
        g1a = fdot2(w.z, hB.z, g1a); g1b = fdot2(w.w, hB.w, g1b);
      }
      #pragma unroll
      for (int m = 0; m < 16; ++m) {
        uint4 w = wh1[m];
        uint4 hA = *(const uint4*)&sh1h[0][4*m];
        uint4 hB = *(const uint4*)&sh1h[1][4*m];
        g0a = fdot2(w.x, hA.x, g0a); g0b = fdot2(w.y, hA.y, g0b);
        g0a = fdot2(w.z, hA.z, g0a); g0b = fdot2(w.w, hA.w, g0b);
        g1a = fdot2(w.x, hB.x, g1a); g1b = fdot2(w.y, hB.y, g1b);
        g1a = fdot2(w.z, hB.z, g1a); g1b = fdot2(w.w, hB.w, g1b);
      }
      gates[0][tid] = g0a + g0b;
      gates[1][tid] = g1a + g1b;
    }
    __syncthreads();                                   // B3
    if (tid < 256) {
      int row = tid >> 7, cell = tid & 127;
      float iv = gates[row][cell],      fv = gates[row][cell+HH],
            qv = gates[row][cell+2*HH], ov = gates[row][cell+3*HH];
      cl1 = sigm(fv)*cl1 + sigm(iv)*tanh_f(qv);
      float hv = sigm(ov)*tanh_f(cl1);
      ((__half*)&sh1h[0][0])[row*128 + cell] = __float2half(hv);
      float p0 = hv*wl0, p1 = hv*wl1, p2 = hv*wl2;
      #pragma unroll
      for (int off = 32; off > 0; off >>= 1) {
        p0 += __shfl_down(p0, off); p1 += __shfl_down(p1, off); p2 += __shfl_down(p2, off);
      }
      if (lane == 0) {
        int w4 = tid >> 6;
        hpart[w4][0] = p0; hpart[w4][1] = p1; hpart[w4][2] = p2;
      }
    }
  }
  __syncthreads();
  if (tid >= 504 && tid < 506) {
    int row = tid - 504;
    float l0 = hpart[2*row][0] + hpart[2*row+1][0] + bl0;
    float l1 = hpart[2*row][1] + hpart[2*row+1][1] + bl1;
    float l2 = hpart[2*row][2] + hpart[2*row+1][2] + bl2;
    float mx = fmaxf(l0, fmaxf(l1, l2));
    float e0=__expf(l0-mx), e1=__expf(l1-mx), e2=__expf(l2-mx);
    float inv = 1.0f/(e0+e1+e2);
    float* dst = alpha_out + (((size_t)(bb+row))*T_LEN + (T_LEN-1))*3;
    dst[0]=e0*inv; dst[1]=e1*inv; dst[2]=e2*inv;
  }
}

// Kalman scan v14 = v13 arithmetic (bit-identical per-output dot chains),
// widened to 512 threads / 8 waves per batch: every strip phase halves its
// per-thread work (strip4->strip2, strip2->strip1), MIX moves to waves 4-7
// (1 slot/thread), r to wave 7 of P2, GJ stays on wave 0. launch_bounds
// (512,4) caps VGPR at 128 -> 2 blocks/CU = 16 waves/CU (vs 8): shorter
// phases + twice the waves to hide barrier skew and LDS latency.
__global__ __launch_bounds__(512, 4) void kalman_kernel(
    const float* __restrict__ a, const float* __restrict__ A,
    const float* __restrict__ C, const float* __restrict__ alpha,
    float* __restrict__ out) {
  __shared__ __align__(16) uint32_t SgH[DZ][20];
  __shared__ __align__(16) uint32_t AmH[2][DZ][20];
  __shared__ __align__(16) uint32_t CmH[2][DA][20];
  __shared__ __align__(16) uint32_t Sp2H[DZ][20];
  __shared__ __align__(16) uint32_t T2H[DZ][20];
  __shared__ __align__(16) uint32_t NnTH[DA][20];
  __shared__ __align__(16) uint32_t NnH[DZ][12];
  __shared__ __align__(16) uint32_t KgH[DZ][12];
  __shared__ __align__(16) uint32_t SinvH[DA][12];
  __shared__ __align__(16) float Aug[DA][36];
  __shared__ __align__(16) float sa[T_LEN][DA];
  __shared__ float salpha[T_LEN*3];
  __shared__ __align__(16) float muvF[DZ], munF[DZ], rv[DA];

  int tid = threadIdx.x;
  int b = blockIdx.x;

  for (int e = tid; e < T_LEN*DA; e += 512) (&sa[0][0])[e] = a[(size_t)b*T_LEN*DA + e];
  for (int e = tid; e < T_LEN*3; e += 512) salpha[e] = alpha[(size_t)b*T_LEN*3 + e];
  __syncthreads();

  const int i32 = tid & 31;
  const int g16 = (tid >> 5) & 15;     // 16 strip groups over 512 threads

  if (tid < 256) {
    int i8 = tid >> 3, jq = tid & 7;
    uint2 iv;
    iv.x = packh2((i8==4*jq  )?1.f:0.f, (i8==4*jq+1)?1.f:0.f);
    iv.y = packh2((i8==4*jq+2)?1.f:0.f, (i8==4*jq+3)?1.f:0.f);
    *(uint2*)&SgH[i8][jq*2] = iv;
    if (tid < DZ) muvF[tid] = 0.0f;
  }

  const float4* A4 = (const float4*)A;
  const float4* C4 = (const float4*)C;
  // Prefetch on waves 4-7: thread 256+u holds Am slot u (row u>>3, quad u&7);
  // u<128 additionally Cm slot u.
  float4 pA0, pA1, pA2, pC0, pC1, pC2;
  if (tid >= 256) {
    int u = tid - 256;
    pA0 = A4[(0*T_LEN + 1)*256 + u];
    pA1 = A4[(1*T_LEN + 1)*256 + u];
    pA2 = A4[(2*T_LEN + 1)*256 + u];
    if (u < 128) {
      pC0 = C4[(0*T_LEN + 0)*128 + u];
      pC1 = C4[(1*T_LEN + 0)*128 + u];
      pC2 = C4[(2*T_LEN + 0)*128 + u];
    }
  }
  #define MIX_AND_PREFETCH(bf, s, sn)                                          \
  if (tid >= 256) {                                                            \
    int u_ = tid - 256, rl_ = u_ >> 3, q_ = u_ & 7;                            \
    int ta_ = ((s) < T_LEN-1) ? (s)+1 : (s);                                   \
    float bA0 = salpha[ta_*3+0], bA1 = salpha[ta_*3+1], bA2 = salpha[ta_*3+2]; \
    float vx = bA0*pA0.x + bA1*pA1.x + bA2*pA2.x;                              \
    float vy = bA0*pA0.y + bA1*pA1.y + bA2*pA2.y;                              \
    float vz = bA0*pA0.z + bA1*pA1.z + bA2*pA2.z;                              \
    float vw = bA0*pA0.w + bA1*pA1.w + bA2*pA2.w;                              \
    uint2 pv; pv.x = packh2(vx, vy); pv.y = packh2(vz, vw);                    \
    *(uint2*)&AmH[bf][rl_][q_*2] = pv;                                         \
    if (u_ < 128) {                                                            \
      float bC0 = salpha[(s)*3+0], bC1 = salpha[(s)*3+1], bC2 = salpha[(s)*3+2]; \
      float cx = bC0*pC0.x + bC1*pC1.x + bC2*pC2.x;                            \
      float cy = bC0*pC0.y + bC1*pC1.y + bC2*pC2.y;                            \
      float cz = bC0*pC0.z + bC1*pC1.z + bC2*pC2.z;                            \
      float cw = bC0*pC0.w + bC1*pC1.w + bC2*pC2.w;                            \
      uint2 pc; pc.x = packh2(cx, cy); pc.y = packh2(cz, cw);                  \
      *(uint2*)&CmH[bf][rl_][q_*2] = pc;                                       \
    }                                                                          \
    int sn_ = ((sn) < T_LEN) ? (sn) : T_LEN-1;                                 \
    int tan_ = (sn_ < T_LEN-1) ? sn_+1 : sn_;                                  \
    pA0 = A4[(0*T_LEN + tan_)*256 + u_];                                       \
    pA1 = A4[(1*T_LEN + tan_)*256 + u_];                                       \
    pA2 = A4[(2*T_LEN + tan_)*256 + u_];                                       \
    if (u_ < 128) {                                                            \
      pC0 = C4[(0*T_LEN + sn_)*128 + u_];                                      \
      pC1 = C4[(1*T_LEN + sn_)*128 + u_];                                      \
      pC2 = C4[(2*T_LEN + sn_)*128 + u_];                                      \
    }                                                                          \
  }

  MIX_AND_PREFETCH(0, 0, 1)
  __syncthreads();

  #pragma unroll 1
  for (int t = 0; t < T_LEN; ++t) {
    const int p = t & 1;

    // ---- P1: N[i32][g16] = dot(Sg_i32, Cm_g16) (strip1); b16 to NnH+NnTH ----
    {
      uint4 s0 = *(const uint4*)&SgH[i32][0];
      uint4 s1 = *(const uint4*)&SgH[i32][4];
      uint4 s2 = *(const uint4*)&SgH[i32][8];
      uint4 s3 = *(const uint4*)&SgH[i32][12];
      uint4 c0 = *(const uint4*)&CmH[p][g16][0];
      uint4 c1 = *(const uint4*)&CmH[p][g16][4];
      uint4 c2 = *(const uint4*)&CmH[p][g16][8];
      uint4 c3 = *(const uint4*)&CmH[p][g16][12];
      float aA = dot8(s3,c3, dot8(s2,c2, dot8(s1,c1, dot8(s0,c0, 0.f))));
      ((__half*)&NnH[0][0])[i32*24 + g16] = __float2half(aA);
      ((__half*)&NnTH[0][0])[g16*40 + i32] = __float2half(aA);
    }
    BAR();                                             // B1

    // ---- P2: Aug = [Cm*Sg*Cm^T + R | I] (tid<256); r on wave 7 ----
    if (tid < 256) {
      int i = tid & 15, j = tid >> 4;
      uint4 c0 = *(const uint4*)&CmH[p][i][0];
      uint4 c1 = *(const uint4*)&CmH[p][i][4];
      uint4 c2 = *(const uint4*)&CmH[p][i][8];
      uint4 c3 = *(const uint4*)&CmH[p][i][12];
      uint4 n0 = *(const uint4*)&NnTH[j][0];
      uint4 n1 = *(const uint4*)&NnTH[j][4];
      uint4 n2 = *(const uint4*)&NnTH[j][8];
      uint4 n3 = *(const uint4*)&NnTH[j][12];
      float s = dot8(c3,n3, dot8(c2,n2, dot8(c1,n1, dot8(c0,n0, 0.f))));
      Aug[i][j] = s + ((i == j) ? 0.01f : 0.0f);
      Aug[i][16 + j] = (i == j) ? 1.0f : 0.0f;
    } else if (tid >= 480 && tid < 480 + DA) {
      int jr = tid - 480;
      uint4 c0 = *(const uint4*)&CmH[p][jr][0];
      uint4 c1 = *(const uint4*)&CmH[p][jr][4];
      uint4 c2 = *(const uint4*)&CmH[p][jr][8];
      uint4 c3 = *(const uint4*)&CmH[p][jr][12];
      const float4* mv = (const float4*)muvF;
      float d = 0.f;
      d = dot8f(c0, mv[0], mv[1], d);
      d = dot8f(c1, mv[2], mv[3], d);
      d = dot8f(c2, mv[4], mv[5], d);
      d = dot8f(c3, mv[6], mv[7], d);
      rv[jr] = sa[t][jr] - d;
    }
    BAR();                                             // B2

    // ---- P3: GJ (wave 0) -> Sinv; MIX(t+1) on waves 4-7 ----
    if (tid < 64) {
      int lane = tid;
      int r = lane >> 2, cb = lane & 3;
      float v[8];
      #pragma unroll
      for (int j = 0; j < 8; ++j) v[j] = Aug[r][cb*8 + j];
      #define GJ_PIVOT(P, CTRL)                                                \
      {                                                                        \
        float App = __int_as_float(__builtin_amdgcn_readlane(                  \
                      __float_as_int(v[(P) & 7]), ((P) << 2) | ((P) >> 3)));   \
        float fv  = __int_as_float(__builtin_amdgcn_mov_dpp(                   \
                      __float_as_int(v[(P) & 7]), (CTRL), 0xf, 0xf, true));    \
        float prow[8];                                                         \
        _Pragma("unroll")                                                      \
        for (int j = 0; j < 8; ++j) prow[j] = __shfl(v[j], ((P) << 2) | cb, 64); \
        float pinv = 1.0f / App;                                               \
        if (r == (P)) {                                                        \
          _Pragma("unroll")                                                    \
          for (int j = 0; j < 8; ++j) v[j] *= pinv;                            \
        } else {                                                               \
          float fp = fv * pinv;                                                \
          _Pragma("unroll")                                                    \
          for (int j = 0; j < 8; ++j) v[j] -= fp * prow[j];                    \
        }                                                                      \
      }
      GJ_PIVOT(0, 0x00)  GJ_PIVOT(1, 0x00)  GJ_PIVOT(2, 0x00)  GJ_PIVOT(3, 0x00)
      GJ_PIVOT(4, 0x00)  GJ_PIVOT(5, 0x00)  GJ_PIVOT(6, 0x00)  GJ_PIVOT(7, 0x00)
      GJ_PIVOT(8, 0x55)  GJ_PIVOT(9, 0x55)  GJ_PIVOT(10, 0x55) GJ_PIVOT(11, 0x55)
      GJ_PIVOT(12, 0x55) GJ_PIVOT(13, 0x55) GJ_PIVOT(14, 0x55) GJ_PIVOT(15, 0x55)
      #undef GJ_PIVOT
      if (cb >= 2) {
        uint4 w;
        w.x = packh2(v[0], v[1]); w.y = packh2(v[2], v[3]);
        w.z = packh2(v[4], v[5]); w.w = packh2(v[6], v[7]);
        *(uint4*)&SinvH[r][(cb-2)*4] = w;
      }
    }
    {
      int s = (t+1 < T_LEN) ? t+1 : T_LEN-1;
      MIX_AND_PREFETCH(p^1, s, t+2)
    }
    BAR();                                             // B3

    // ---- P4: Kg[i32][g16] = dot(Nn_i32, Sinv_g16) (strip1) ----
    {
      uint4 n0 = *(const uint4*)&NnH[i32][0];
      uint4 n1 = *(const uint4*)&NnH[i32][4];
      uint4 s0 = *(const uint4*)&SinvH[g16][0];
      uint4 s1 = *(const uint4*)&SinvH[g16][4];
      float k = dot8(n1, s1, dot8(n0, s0, 0.f));
      ((__half*)&KgH[0][0])[i32*24 + g16] = __float2half(k);
    }
    BAR();                                             // B4

    // ---- P5: Sp2 = Sg - Kg*Nn^T (strip2); mu+ & out dual-duty wave 2 ----
    {
      uint4 k0 = *(const uint4*)&KgH[i32][0];
      uint4 k1 = *(const uint4*)&KgH[i32][4];
      float acc[2];
      #pragma unroll
      for (int c = 0; c < 2; ++c) {
        uint4 b0 = *(const uint4*)&NnH[2*g16+c][0];
        uint4 b1 = *(const uint4*)&NnH[2*g16+c][4];
        acc[c] = dot8(k1, b1, dot8(k0, b0, 0.f));
      }
      uint32_t sgp = SgH[i32][g16];
      SgH[i32][g16] = sgp;  // keep read before write ordering trivial (no-op)
      Sp2H[i32][g16] = packh2(h2lo(sgp) - acc[0], h2hi(sgp) - acc[1]);
    }
    if (tid >= 128 && tid < 128 + DZ) {
      int q = tid - 128;
      uint4 k0 = *(const uint4*)&KgH[q][0];
      uint4 k1 = *(const uint4*)&KgH[q][4];
      const float4* rp = (const float4*)rv;
      float m = muvF[q];
      m = dot8f(k0, rp[0], rp[1], m);
      m = dot8f(k1, rp[2], rp[3], m);
      munF[q] = m;
      out[((size_t)b*T_LEN + t)*DZ + q] = m;
    }
    BAR();                                             // B5

    // ---- P6: T2[i32][2g16..2g16+1] = dot(Am_i32, Sp2_col) (strip2) ----
    {
      uint4 a0 = *(const uint4*)&AmH[p][i32][0];
      uint4 a1 = *(const uint4*)&AmH[p][i32][4];
      uint4 a2 = *(const uint4*)&AmH[p][i32][8];
      uint4 a3 = *(const uint4*)&AmH[p][i32][12];
      float acc[2];
      #pragma unroll
      for (int c = 0; c < 2; ++c) {
        uint4 p0 = *(const uint4*)&Sp2H[2*g16+c][0];
        uint4 p1 = *(const uint4*)&Sp2H[2*g16+c][4];
        uint4 p2 = *(const uint4*)&Sp2H[2*g16+c][8];
        uint4 p3 = *(const uint4*)&Sp2H[2*g16+c][12];
        acc[c] = dot8(a3,p3, dot8(a2,p2, dot8(a1,p1, dot8(a0,p0, 0.f))));
      }
      T2H[i32][g16] = packh2(acc[0], acc[1]);
    }
    BAR();                                             // B6

    // ---- P7: Sg' = T2*Am^T + Q (strip2); mu_pred dual-duty wave 2 ----
    {
      uint4 t0 = *(const uint4*)&T2H[i32][0];
      uint4 t1 = *(const uint4*)&T2H[i32][4];
      uint4 t2 = *(const uint4*)&T2H[i32][8];
      uint4 t3 = *(const uint4*)&T2H[i32][12];
      float acc[2];
      #pragma unroll
      for (int c = 0; c < 2; ++c) {
        uint4 a0 = *(const uint4*)&AmH[p][2*g16+c][0];
        uint4 a1 = *(const uint4*)&AmH[p][2*g16+c][4];
        uint4 a2 = *(const uint4*)&AmH[p][2*g16+c][8];
        uint4 a3 = *(const uint4*)&AmH[p][2*g16+c][12];
        acc[c] = dot8(t3,a3, dot8(t2,a2, dot8(t1,a1, dot8(t0,a0, 0.f))));
        if (i32 == 2*g16 + c) acc[c] += 0.01f;
      }
      SgH[i32][g16] = packh2(acc[0], acc[1]);
    }
    if (tid >= 128 && tid < 128 + DZ) {
      int q = tid - 128;
      uint4 a0 = *(const uint4*)&AmH[p][q][0];
      uint4 a1 = *(const uint4*)&AmH[p][q][4];
      uint4 a2 = *(const uint4*)&AmH[p][q][8];
      uint4 a3 = *(const uint4*)&AmH[p][q][12];
      const float4* mp = (const float4*)munF;
      float m = 0.f;
      m = dot8f(a0, mp[0], mp[1], m);
      m = dot8f(a1, mp[2], mp[3], m);
      m = dot8f(a2, mp[4], mp[5], m);
      m = dot8f(a3, mp[6], mp[7], m);
      muvF[q] = m;
    }
    BAR();                                             // B7
  }
  #undef MIX_AND_PREFETCH
}

extern "C" void kernel_launch(void* const* d_in, const int* in_sizes, int n_in,
                              void* d_out, int out_size, void* d_ws, size_t ws_size,
                              hipStream_t stream) {
  const float* a    = (const float*)d_in[0];
  const float* A    = (const float*)d_in[1];
  const float* C    = (const float*)d_in[2];
  const float* a0   = (const float*)d_in[3];
  const float* Wih0 = (const float*)d_in[4];
  const float* Whh0 = (const float*)d_in[5];
  const float* bih0 = (const float*)d_in[6];
  const float* bhh0 = (const float*)d_in[7];
  const float* Wih1 = (const float*)d_in[8];
  const float* Whh1 = (const float*)d_in[9];
  const float* bih1 = (const float*)d_in[10];
  const float* bhh1 = (const float*)d_in[11];
  const float* Wlin = (const float*)d_in[12];
  const float* blin = (const float*)d_in[13];
  uint32_t* ws = (uint32_t*)d_ws;
  float* alpha = (float*)(ws + 103424);
  float* out = (float*)d_out;

  prep_kernel<<<404, 256, 0, stream>>>(Wih0, Whh0, bih0, bhh0, Wih1, Whh1, bih1, bhh1, ws);
  lstm_kernel<<<256, 512, 0, stream>>>(a, a0, ws, Wlin, blin, alpha);
  kalman_kernel<<<512, 512, 0, stream>>>(a, A, C, alpha, out);
}

// Round 12
// 1016.468 us; speedup vs baseline: 1.0068x; 1.0068x over previous
//
#include <hip/hip_runtime.h>
#include <hip/hip_fp16.h>
#include <cstdint>

#define T_LEN 128
#define DA    16
#define DZ    32
#define HH    128

__device__ __forceinline__ float sigm(float x){ return 1.0f/(1.0f + __expf(-x)); }
__device__ __forceinline__ float tanh_f(float x){ return 1.0f - 2.0f/(__expf(2.0f*x)+1.0f); }

typedef _Float16 h2v __attribute__((ext_vector_type(2)));
__device__ __forceinline__ float fdot2(uint32_t w, uint32_t h, float acc){
  union{uint32_t u; h2v v;} a, b; a.u = w; b.u = h;
  return __builtin_amdgcn_fdot2(a.v, b.v, acc, false);
}
__device__ __forceinline__ uint32_t packh2(float x, float y){
  return (uint32_t)__half_as_ushort(__float2half(x)) |
         ((uint32_t)__half_as_ushort(__float2half(y)) << 16);
}
__device__ __forceinline__ float h2lo(uint32_t u){
  return __half2float(__ushort_as_half((unsigned short)(u & 0xffffu)));
}
__device__ __forceinline__ float h2hi(uint32_t u){
  return __half2float(__ushort_as_half((unsigned short)(u >> 16)));
}
__device__ __forceinline__ float dot8(uint4 a, uint4 b, float acc){
  acc = fdot2(a.x, b.x, acc); acc = fdot2(a.y, b.y, acc);
  acc = fdot2(a.z, b.z, acc); acc = fdot2(a.w, b.w, acc);
  return acc;
}
__device__ __forceinline__ float dot8f(uint4 h, float4 f0, float4 f1, float acc){
  acc += h2lo(h.x)*f0.x + h2hi(h.x)*f0.y + h2lo(h.y)*f0.z + h2hi(h.y)*f0.w;
  acc += h2lo(h.z)*f1.x + h2hi(h.z)*f1.y + h2lo(h.w)*f1.z + h2hi(h.w)*f1.w;
  return acc;
}

// LDS-only barrier: drain LDS pipe, raw s_barrier (no vmcnt drain).
#define BAR() do { asm volatile("s_waitcnt lgkmcnt(0)" ::: "memory"); \
                   __builtin_amdgcn_s_barrier(); } while (0)

__global__ void prep_kernel(const float* __restrict__ Wih0, const float* __restrict__ Whh0,
                            const float* __restrict__ bih0, const float* __restrict__ bhh0,
                            const float* __restrict__ Wih1, const float* __restrict__ Whh1,
                            const float* __restrict__ bih1, const float* __restrict__ bhh1,
                            uint32_t* __restrict__ ws) {
  int idx = blockIdx.x*256 + threadIdx.x;
  if (idx < 4096) {
    int q = idx & 3, g = (idx >> 2) & 511, m = idx >> 11;
    int k0 = 8*m + 2*q;
    ws[idx] = packh2(Wih0[g*DA + k0], Wih0[g*DA + k0 + 1]);
  } else if (idx < 36864) {
    int f = idx - 4096;
    int q = f & 3, g = (f >> 2) & 511, m = f >> 11;
    int k0 = 8*m + 2*q;
    ws[idx] = packh2(Whh0[g*HH + k0], Whh0[g*HH + k0 + 1]);
  } else if (idx < 69632) {
    int f = idx - 36864;
    int q = f & 3, g = (f >> 2) & 511, m = f >> 11;
    int k0 = 8*m + 2*q;
    ws[idx] = packh2(Wih1[g*HH + k0], Wih1[g*HH + k0 + 1]);
  } else if (idx < 102400) {
    int f = idx - 69632;
    int q = f & 3, g = (f >> 2) & 511, m = f >> 11;
    int k0 = 8*m + 2*q;
    ws[idx] = packh2(Whh1[g*HH + k0], Whh1[g*HH + k0 + 1]);
  } else if (idx < 102912) {
    int j = idx - 102400;
    ((float*)ws)[idx] = bih0[j] + bhh0[j];
  } else if (idx < 103424) {
    int j = idx - 102912;
    ((float*)ws)[idx] = bih1[j] + bhh1[j];
  }
}

// Persistent 2-layer LSTM (round-8 version).
__global__ __launch_bounds__(512, 2) void lstm_kernel(
    const float* __restrict__ a, const float* __restrict__ a0,
    const uint32_t* __restrict__ wsw, const float* __restrict__ Wlin,
    const float* __restrict__ blin, float* __restrict__ alpha_out) {
  const uint4* Wih0p = (const uint4*)(wsw);
  const uint4* Whh0p = (const uint4*)(wsw + 4096);
  const uint4* Wih1p = (const uint4*)(wsw + 36864);
  const uint4* Whh1p = (const uint4*)(wsw + 69632);
  const float* b0v = (const float*)(wsw + 102400);
  const float* b1v = (const float*)(wsw + 102912);

  __shared__ __align__(16) uint32_t sxh[2][T_LEN][8];
  __shared__ __align__(16) uint32_t sh0h[2][64];
  __shared__ __align__(16) uint32_t sh1h[2][64];
  __shared__ float gates[2][4*HH];
  __shared__ float hpart[4][3];

  int tid = threadIdx.x;
  int lane = tid & 63;
  int wv = tid >> 6;
  int bb = blockIdx.x * 2;

  uint4 wi0[2], wh0[16], wi1[16], wh1[16];
  #pragma unroll
  for (int m = 0; m < 2; ++m)  wi0[m] = Wih0p[m*512 + tid];
  #pragma unroll
  for (int m = 0; m < 16; ++m) wh0[m] = Whh0p[m*512 + tid];
  #pragma unroll
  for (int m = 0; m < 16; ++m) wi1[m] = Wih1p[m*512 + tid];
  #pragma unroll
  for (int m = 0; m < 16; ++m) wh1[m] = Whh1p[m*512 + tid];
  float bi0 = b0v[tid], bi1 = b1v[tid];

  for (int i = tid; i < 2*T_LEN*8; i += 512) {
    int r = i / (T_LEN*8), rem = i % (T_LEN*8), t = rem >> 3, p = rem & 7;
    float x0, x1;
    if (t == 0) { x0 = a0[2*p]; x1 = a0[2*p+1]; }
    else {
      const float* src = a + ((size_t)(bb + r)*T_LEN + (t-1))*DA;
      x0 = src[2*p]; x1 = src[2*p+1];
    }
    sxh[r][t][p] = packh2(x0, x1);
  }
  float wl0 = Wlin[0*HH + (tid & 127)];
  float wl1 = Wlin[1*HH + (tid & 127)];
  float wl2 = Wlin[2*HH + (tid & 127)];
  float bl0 = blin[0], bl1 = blin[1], bl2 = blin[2];
  float cl0 = 0.f, cl1 = 0.f;
  if (tid < 128) { sh0h[wv][lane] = 0u; sh1h[wv][lane] = 0u; }
  __syncthreads();

  #pragma unroll 1
  for (int t = 0; t < T_LEN; ++t) {
    {
      float g0a = bi0, g0b = 0.f, g1a = bi0, g1b = 0.f;
      uint4 xA0 = *(const uint4*)&sxh[0][t][0];
      uint4 xA1 = *(const uint4*)&sxh[0][t][4];
      uint4 xB0 = *(const uint4*)&sxh[1][t][0];
      uint4 xB1 = *(const uint4*)&sxh[1][t][4];
      g0a = fdot2(wi0[0].x, xA0.x, g0a); g0b = fdot2(wi0[0].y, xA0.y, g0b);
      g0a = fdot2(wi0[0].z, xA0.z, g0a); g0b = fdot2(wi0[0].w, xA0.w, g0b);
      g0a = fdot2(wi0[1].x, xA1.x, g0a); g0b = fdot2(wi0[1].y, xA1.y, g0b);
      g0a = fdot2(wi0[1].z, xA1.z, g0a); g0b = fdot2(wi0[1].w, xA1.w, g0b);
      g1a = fdot2(wi0[0].x, xB0.x, g1a); g1b = fdot2(wi0[0].y, xB0.y, g1b);
      g1a = fdot2(wi0[0].z, xB0.z, g1a); g1b = fdot2(wi0[0].w, xB0.w, g1b);
      g1a = fdot2(wi0[1].x, xB1.x, g1a); g1b = fdot2(wi0[1].y, xB1.y, g1b);
      g1a = fdot2(wi0[1].z, xB1.z, g1a); g1b = fdot2(wi0[1].w, xB1.w, g1b);
      #pragma unroll
      for (int m = 0; m < 16; ++m) {
        uint4 w = wh0[m];
        uint4 hA = *(const uint4*)&sh0h[0][4*m];
        uint4 hB = *(const uint4*)&sh0h[1][4*m];
        g0a = fdot2(w.x, hA.x, g0a); g0b = fdot2(w.y, hA.y, g0b);
        g0a = fdot2(w.z, hA.z, g0a); g0b = fdot2(w.w, hA.w, g0b);
        g1a = fdot2(w.x, hB.x, g1a); g1b = fdot2(w.y, hB.y, g1b);
        g1a = fdot2(w.z, hB.z, g1a); g1b = fdot2(w.w, hB.w, g1b);
      }
      gates[0][tid] = g0a + g0b;
      gates[1][tid] = g1a + g1b;
    }
    __syncthreads();                                   // B1
    if (t > 0 && tid >= 504 && tid < 506) {
      int row = tid - 504;
      float l0 = hpart[2*row][0] + hpart[2*row+1][0] + bl0;
      float l1 = hpart[2*row][1] + hpart[2*row+1][1] + bl1;
      float l2 = hpart[2*row][2] + hpart[2*row+1][2] + bl2;
      float mx = fmaxf(l0, fmaxf(l1, l2));
      float e0=__expf(l0-mx), e1=__expf(l1-mx), e2=__expf(l2-mx);
      float inv = 1.0f/(e0+e1+e2);
      float* dst = alpha_out + (((size_t)(bb+row))*T_LEN + (t-1))*3;
      dst[0]=e0*inv; dst[1]=e1*inv; dst[2]=e2*inv;
    }
    if (tid < 256) {
      int row = tid >> 7, cell = tid & 127;
      float iv = gates[row][cell],      fv = gates[row][cell+HH],
            qv = gates[row][cell+2*HH], ov = gates[row][cell+3*HH];
      cl0 = sigm(fv)*cl0 + sigm(iv)*tanh_f(qv);
      float hv = sigm(ov)*tanh_f(cl0);
      ((__half*)&sh0h[0][0])[row*128 + cell] = __float2half(hv);
    }
    __syncthreads();                                   // B2
    {
      float g0a = bi1, g0b = 0.f, g1a = bi1, g1b = 0.f;
      #pragma unroll
      for (int m = 0; m < 16; ++m) {
        uint4 w = wi1[m];
        uint4 hA = *(const uint4*)&sh0h[0][4*m];
        uint4 hB = *(const uint4*)&sh0h[1][4*m];
        g0a = fdot2(w.x, hA.x, g0a); g0b = fdot2(w.y, hA.y, g0b);
        g0a = fdot2(w.z, hA.z, g0a); g0b = fdot2(w.w, hA.w, g0b);
        g1a = fdot2(w.x, hB.x, g1a); g1b = fdot2(w.y, hB.y, g1b);
        g1a = fdot2(w.z, hB.z, g1a); g1b = fdot2(w.w, hB.w, g1b);
      }
      #pragma unroll
      for (int m = 0; m < 16; ++m) {
        uint4 w = wh1[m];
        uint4 hA = *(const uint4*)&sh1h[0][4*m];
        uint4 hB = *(const uint4*)&sh1h[1][4*m];
        g0a = fdot2(w.x, hA.x, g0a); g0b = fdot2(w.y, hA.y, g0b);
        g0a = fdot2(w.z, hA.z, g0a); g0b = fdot2(w.w, hA.w, g0b);
        g1a = fdot2(w.x, hB.x, g1a); g1b = fdot2(w.y, hB.y, g1b);
        g1a = fdot2(w.z, hB.z, g1a); g1b = fdot2(w.w, hB.w, g1b);
      }
      gates[0][tid] = g0a + g0b;
      gates[1][tid] = g1a + g1b;
    }
    __syncthreads();                                   // B3
    if (tid < 256) {
      int row = tid >> 7, cell = tid & 127;
      float iv = gates[row][cell],      fv = gates[row][cell+HH],
            qv = gates[row][cell+2*HH], ov = gates[row][cell+3*HH];
      cl1 = sigm(fv)*cl1 + sigm(iv)*tanh_f(qv);
      float hv = sigm(ov)*tanh_f(cl1);
      ((__half*)&sh1h[0][0])[row*128 + cell] = __float2half(hv);
      float p0 = hv*wl0, p1 = hv*wl1, p2 = hv*wl2;
      #pragma unroll
      for (int off = 32; off > 0; off >>= 1) {
        p0 += __shfl_down(p0, off); p1 += __shfl_down(p1, off); p2 += __shfl_down(p2, off);
      }
      if (lane == 0) {
        int w4 = tid >> 6;
        hpart[w4][0] = p0; hpart[w4][1] = p1; hpart[w4][2] = p2;
      }
    }
  }
  __syncthreads();
  if (tid >= 504 && tid < 506) {
    int row = tid - 504;
    float l0 = hpart[2*row][0] + hpart[2*row+1][0] + bl0;
    float l1 = hpart[2*row][1] + hpart[2*row+1][1] + bl1;
    float l2 = hpart[2*row][2] + hpart[2*row+1][2] + bl2;
    float mx = fmaxf(l0, fmaxf(l1, l2));
    float e0=__expf(l0-mx), e1=__expf(l1-mx), e2=__expf(l2-mx);
    float inv = 1.0f/(e0+e1+e2);
    float* dst = alpha_out + (((size_t)(bb+row))*T_LEN + (T_LEN-1))*3;
    dst[0]=e0*inv; dst[1]=e1*inv; dst[2]=e2*inv;
  }
}

// Kalman scan v13 (round-10 verified best: 621us, absmax 0.1328125).
// v11 arithmetic; MIX hidden under the serial wave-0 GJ on waves 2-3.
// Structural floor analysis (rounds 9-11): 7 barrier-quanta x ~120cyc LDS
// round-trip + ~1.3K serial GJ + issue ~= 5.8K cyc/step. Widening to 512
// threads regressed (+bank conflicts, costlier barriers); fusing Kg into GJ
// regressed (wave-0 serial has 2x leverage); phase-count is chain-limited.
__global__ __launch_bounds__(256) void kalman_kernel(
    const float* __restrict__ a, const float* __restrict__ A,
    const float* __restrict__ C, const float* __restrict__ alpha,
    float* __restrict__ out) {
  __shared__ __align__(16) uint32_t SgH[DZ][20];
  __shared__ __align__(16) uint32_t AmH[2][DZ][20];
  __shared__ __align__(16) uint32_t CmH[2][DA][20];
  __shared__ __align__(16) uint32_t Sp2H[DZ][20];
  __shared__ __align__(16) uint32_t T2H[DZ][20];
  __shared__ __align__(16) uint32_t NnTH[DA][20];
  __shared__ __align__(16) uint32_t NnH[DZ][12];
  __shared__ __align__(16) uint32_t KgH[DZ][12];
  __shared__ __align__(16) uint32_t SinvH[DA][12];
  __shared__ __align__(16) float Aug[DA][36];
  __shared__ __align__(16) float sa[T_LEN][DA];
  __shared__ float salpha[T_LEN*3];
  __shared__ __align__(16) float muvF[DZ], munF[DZ], rv[DA];

  int tid = threadIdx.x;
  int b = blockIdx.x;

  for (int e = tid; e < T_LEN*DA; e += 256) (&sa[0][0])[e] = a[(size_t)b*T_LEN*DA + e];
  for (int e = tid; e < T_LEN*3; e += 256) salpha[e] = alpha[(size_t)b*T_LEN*3 + e];
  __syncthreads();

  const int i8 = tid >> 3, jq = tid & 7;
  const int i32 = tid & 31, g = tid >> 5;
  const int j2 = g * 2, j4 = g * 4;

  {
    uint2 iv;
    iv.x = packh2((i8==4*jq  )?1.f:0.f, (i8==4*jq+1)?1.f:0.f);
    iv.y = packh2((i8==4*jq+2)?1.f:0.f, (i8==4*jq+3)?1.f:0.f);
    *(uint2*)&SgH[i8][jq*2] = iv;
    if (tid < DZ) muvF[tid] = 0.0f;
  }

  const float4* A4 = (const float4*)A;
  const float4* C4 = (const float4*)C;
  // Prefetch re-homed to waves 2-3: thread 128+u holds Am slots u (row u>>3)
  // and u+128 (row u>>3 + 16), quad u&7; plus Cm slot u (row u>>3, quad u&7).
  float4 pAl0, pAl1, pAl2, pAh0, pAh1, pAh2, pC0, pC1, pC2;
  if (tid >= 128) {
    int u = tid - 128;
    pAl0 = A4[(0*T_LEN + 1)*256 + u];
    pAl1 = A4[(1*T_LEN + 1)*256 + u];
    pAl2 = A4[(2*T_LEN + 1)*256 + u];
    pAh0 = A4[(0*T_LEN + 1)*256 + u + 128];
    pAh1 = A4[(1*T_LEN + 1)*256 + u + 128];
    pAh2 = A4[(2*T_LEN + 1)*256 + u + 128];
    pC0 = C4[(0*T_LEN + 0)*128 + u];
    pC1 = C4[(1*T_LEN + 0)*128 + u];
    pC2 = C4[(2*T_LEN + 0)*128 + u];
  }
  // MIX(s) into buffer bf (threads 128..255 only); then prefetch step sn.
  #define MIX_AND_PREFETCH(bf, s, sn)                                          \
  if (tid >= 128) {                                                            \
    int u_ = tid - 128, rl_ = u_ >> 3, q_ = u_ & 7;                            \
    int ta_ = ((s) < T_LEN-1) ? (s)+1 : (s);                                   \
    float bA0 = salpha[ta_*3+0], bA1 = salpha[ta_*3+1], bA2 = salpha[ta_*3+2]; \
    float bC0 = salpha[(s)*3+0], bC1 = salpha[(s)*3+1], bC2 = salpha[(s)*3+2]; \
    float vx = bA0*pAl0.x + bA1*pAl1.x + bA2*pAl2.x;                           \
    float vy = bA0*pAl0.y + bA1*pAl1.y + bA2*pAl2.y;                           \
    float vz = bA0*pAl0.z + bA1*pAl1.z + bA2*pAl2.z;                           \
    float vw = bA0*pAl0.w + bA1*pAl1.w + bA2*pAl2.w;                           \
    uint2 pv; pv.x = packh2(vx, vy); pv.y = packh2(vz, vw);                    \
    *(uint2*)&AmH[bf][rl_][q_*2] = pv;                                         \
    vx = bA0*pAh0.x + bA1*pAh1.x + bA2*pAh2.x;                                 \
    vy = bA0*pAh0.y + bA1*pAh1.y + bA2*pAh2.y;                                 \
    vz = bA0*pAh0.z + bA1*pAh1.z + bA2*pAh2.z;                                 \
    vw = bA0*pAh0.w + bA1*pAh1.w + bA2*pAh2.w;                                 \
    pv.x = packh2(vx, vy); pv.y = packh2(vz, vw);                              \
    *(uint2*)&AmH[bf][rl_ + 16][q_*2] = pv;                                    \
    float cx = bC0*pC0.x + bC1*pC1.x + bC2*pC2.x;                              \
    float cy = bC0*pC0.y + bC1*pC1.y + bC2*pC2.y;                              \
    float cz = bC0*pC0.z + bC1*pC1.z + bC2*pC2.z;                              \
    float cw = bC0*pC0.w + bC1*pC1.w + bC2*pC2.w;                              \
    uint2 pc; pc.x = packh2(cx, cy); pc.y = packh2(cz, cw);                    \
    *(uint2*)&CmH[bf][rl_][q_*2] = pc;                                         \
    int sn_ = ((sn) < T_LEN) ? (sn) : T_LEN-1;                                 \
    int tan_ = (sn_ < T_LEN-1) ? sn_+1 : sn_;                                  \
    pAl0 = A4[(0*T_LEN + tan_)*256 + u_];                                      \
    pAl1 = A4[(1*T_LEN + tan_)*256 + u_];                                      \
    pAl2 = A4[(2*T_LEN + tan_)*256 + u_];                                      \
    pAh0 = A4[(0*T_LEN + tan_)*256 + u_ + 128];                                \
    pAh1 = A4[(1*T_LEN + tan_)*256 + u_ + 128];                                \
    pAh2 = A4[(2*T_LEN + tan_)*256 + u_ + 128];                                \
    pC0 = C4[(0*T_LEN + sn_)*128 + u_];                                        \
    pC1 = C4[(1*T_LEN + sn_)*128 + u_];                                        \
    pC2 = C4[(2*T_LEN + sn_)*128 + u_];                                        \
  }

  // pre-loop: mix step 0 into buffer 0; prefetch step 1
  MIX_AND_PREFETCH(0, 0, 1)
  __syncthreads();

  #pragma unroll 1
  for (int t = 0; t < T_LEN; ++t) {
    const int p = t & 1;

    // ---- P1: N[i][j] = dot(Sg_i, Cm_j) (strip2); NnT scatter ----
    {
      uint4 s0 = *(const uint4*)&SgH[i32][0];
      uint4 s1 = *(const uint4*)&SgH[i32][4];
      uint4 s2 = *(const uint4*)&SgH[i32][8];
      uint4 s3 = *(const uint4*)&SgH[i32][12];
      uint4 cA0 = *(const uint4*)&CmH[p][j2][0];
      uint4 cA1 = *(const uint4*)&CmH[p][j2][4];
      uint4 cA2 = *(const uint4*)&CmH[p][j2][8];
      uint4 cA3 = *(const uint4*)&CmH[p][j2][12];
      uint4 cB0 = *(const uint4*)&CmH[p][j2+1][0];
      uint4 cB1 = *(const uint4*)&CmH[p][j2+1][4];
      uint4 cB2 = *(const uint4*)&CmH[p][j2+1][8];
      uint4 cB3 = *(const uint4*)&CmH[p][j2+1][12];
      float aA = dot8(s3,cA3, dot8(s2,cA2, dot8(s1,cA1, dot8(s0,cA0, 0.f))));
      float aB = dot8(s3,cB3, dot8(s2,cB2, dot8(s1,cB1, dot8(s0,cB0, 0.f))));
      NnH[i32][g] = packh2(aA, aB);
      __half* ntp = (__half*)&NnTH[0][0];
      ntp[j2*40 + i32]     = __float2half(aA);
      ntp[(j2+1)*40 + i32] = __float2half(aB);
    }
    BAR();                                             // B1

    // ---- P2: Aug = [Cm*Sg*Cm^T + R | I] ----
    {
      int i = tid & 15, j = tid >> 4;
      uint4 c0 = *(const uint4*)&CmH[p][i][0];
      uint4 c1 = *(const uint4*)&CmH[p][i][4];
      uint4 c2 = *(const uint4*)&CmH[p][i][8];
      uint4 c3 = *(const uint4*)&CmH[p][i][12];
      uint4 n0 = *(const uint4*)&NnTH[j][0];
      uint4 n1 = *(const uint4*)&NnTH[j][4];
      uint4 n2 = *(const uint4*)&NnTH[j][8];
      uint4 n3 = *(const uint4*)&NnTH[j][12];
      float s = dot8(c3,n3, dot8(c2,n2, dot8(c1,n1, dot8(c0,n0, 0.f))));
      Aug[i][j] = s + ((i == j) ? 0.01f : 0.0f);
      Aug[i][16 + j] = (i == j) ? 1.0f : 0.0f;
    }
    BAR();                                             // B2

    // ---- P3: GJ (wave 0) -> Sinv h2; r (wave 1); MIX(t+1) (waves 2-3) ----
    if (tid < 64) {
      int lane = tid;
      int r = lane >> 2, cb = lane & 3;
      float v[8];
      #pragma unroll
      for (int j = 0; j < 8; ++j) v[j] = Aug[r][cb*8 + j];
      #define GJ_PIVOT(P, CTRL)                                                \
      {                                                                        \
        float App = __int_as_float(__builtin_amdgcn_readlane(                  \
                      __float_as_int(v[(P) & 7]), ((P) << 2) | ((P) >> 3)));   \
        float fv  = __int_as_float(__builtin_amdgcn_mov_dpp(                   \
                      __float_as_int(v[(P) & 7]), (CTRL), 0xf, 0xf, true));    \
        float prow[8];                                                         \
        _Pragma("unroll")                                                      \
        for (int j = 0; j < 8; ++j) prow[j] = __shfl(v[j], ((P) << 2) | cb, 64); \
        float pinv = 1.0f / App;                                               \
        if (r == (P)) {                                                        \
          _Pragma("unroll")                                                    \
          for (int j = 0; j < 8; ++j) v[j] *= pinv;                            \
        } else {                                                               \
          float fp = fv * pinv;                                                \
          _Pragma("unroll")                                                    \
          for (int j = 0; j < 8; ++j) v[j] -= fp * prow[j];                    \
        }                                                                      \
      }
      GJ_PIVOT(0, 0x00)  GJ_PIVOT(1, 0x00)  GJ_PIVOT(2, 0x00)  GJ_PIVOT(3, 0x00)
      GJ_PIVOT(4, 0x00)  GJ_PIVOT(5, 0x00)  GJ_PIVOT(6, 0x00)  GJ_PIVOT(7, 0x00)
      GJ_PIVOT(8, 0x55)  GJ_PIVOT(9, 0x55)  GJ_PIVOT(10, 0x55) GJ_PIVOT(11, 0x55)
      GJ_PIVOT(12, 0x55) GJ_PIVOT(13, 0x55) GJ_PIVOT(14, 0x55) GJ_PIVOT(15, 0x55)
      #undef GJ_PIVOT
      if (cb >= 2) {
        uint4 w;
        w.x = packh2(v[0], v[1]); w.y = packh2(v[2], v[3]);
        w.z = packh2(v[4], v[5]); w.w = packh2(v[6], v[7]);
        *(uint4*)&SinvH[r][(cb-2)*4] = w;
      }
    } else if (tid < 64 + DA) {
      int j = tid - 64;
      uint4 c0 = *(const uint4*)&CmH[p][j][0];
      uint4 c1 = *(const uint4*)&CmH[p][j][4];
      uint4 c2 = *(const uint4*)&CmH[p][j][8];
      uint4 c3 = *(const uint4*)&CmH[p][j][12];
      const float4* mv = (const float4*)muvF;
      float4 m0 = mv[0], m1 = mv[1], m2 = mv[2], m3 = mv[3];
      float4 m4 = mv[4], m5 = mv[5], m6 = mv[6], m7 = mv[7];
      float d = 0.f;
      d = dot8f(c0, m0, m1, d);
      d = dot8f(c1, m2, m3, d);
      d = dot8f(c2, m4, m5, d);
      d = dot8f(c3, m6, m7, d);
      rv[j] = sa[t][j] - d;
    }
    {
      int s = (t+1 < T_LEN) ? t+1 : T_LEN-1;
      MIX_AND_PREFETCH(p^1, s, t+2)
    }
    BAR();                                             // B3

    // ---- P4: Kg[i][j] = dot(Nn_i, Sinv_j) (strip2) ----
    {
      uint4 n0 = *(const uint4*)&NnH[i32][0];
      uint4 n1 = *(const uint4*)&NnH[i32][4];
      uint4 sA0 = *(const uint4*)&SinvH[j2][0];
      uint4 sA1 = *(const uint4*)&SinvH[j2][4];
      uint4 sB0 = *(const uint4*)&SinvH[j2+1][0];
      uint4 sB1 = *(const uint4*)&SinvH[j2+1][4];
      float aA = dot8(n1, sA1, dot8(n0, sA0, 0.f));
      float aB = dot8(n1, sB1, dot8(n0, sB0, 0.f));
      KgH[i32][g] = packh2(aA, aB);
    }
    BAR();                                             // B4

    // ---- P5: Sp2 = Sg - Kg*Nn^T (strip4); mu+ & out on wave 2 ----
    {
      uint4 k0 = *(const uint4*)&KgH[i32][0];
      uint4 k1 = *(const uint4*)&KgH[i32][4];
      float acc[4];
      #pragma unroll
      for (int c = 0; c < 4; ++c) {
        uint4 b0 = *(const uint4*)&NnH[j4+c][0];
        uint4 b1 = *(const uint4*)&NnH[j4+c][4];
        acc[c] = dot8(k1, b1, dot8(k0, b0, 0.f));
      }
      uint2 sgp = *(const uint2*)&SgH[i32][g*2];
      uint2 o;
      o.x = packh2(h2lo(sgp.x) - acc[0], h2hi(sgp.x) - acc[1]);
      o.y = packh2(h2lo(sgp.y) - acc[2], h2hi(sgp.y) - acc[3]);
      *(uint2*)&Sp2H[i32][g*2] = o;
    }
    if (tid >= 128 && tid < 128 + DZ) {
      int q = tid - 128;
      uint4 k0 = *(const uint4*)&KgH[q][0];
      uint4 k1 = *(const uint4*)&KgH[q][4];
      const float4* rp = (const float4*)rv;
      float4 r0 = rp[0], r1 = rp[1], r2 = rp[2], r3 = rp[3];
      float m = muvF[q];
      m = dot8f(k0, r0, r1, m);
      m = dot8f(k1, r2, r3, m);
      munF[q] = m;
      out[((size_t)b*T_LEN + t)*DZ + q] = m;
    }
    BAR();                                             // B5

    // ---- P6: T2[i][j] = dot(Am_i, Sp2_j) (strip4) ----
    {
      uint4 a0 = *(const uint4*)&AmH[p][i32][0];
      uint4 a1 = *(const uint4*)&AmH[p][i32][4];
      uint4 a2 = *(const uint4*)&AmH[p][i32][8];
      uint4 a3 = *(const uint4*)&AmH[p][i32][12];
      float acc[4];
      #pragma unroll
      for (int c = 0; c < 4; ++c) {
        uint4 p0 = *(const uint4*)&Sp2H[j4+c][0];
        uint4 p1 = *(const uint4*)&Sp2H[j4+c][4];
        uint4 p2 = *(const uint4*)&Sp2H[j4+c][8];
        uint4 p3 = *(const uint4*)&Sp2H[j4+c][12];
        acc[c] = dot8(a3,p3, dot8(a2,p2, dot8(a1,p1, dot8(a0,p0, 0.f))));
      }
      uint2 o; o.x = packh2(acc[0], acc[1]); o.y = packh2(acc[2], acc[3]);
      *(uint2*)&T2H[i32][g*2] = o;
    }
    BAR();                                             // B6

    // ---- P7: Sg' = T2*Am^T + Q (strip4); mu_pred (wave 2) ----
    {
      uint4 t0 = *(const uint4*)&T2H[i32][0];
      uint4 t1 = *(const uint4*)&T2H[i32][4];
      uint4 t2 = *(const uint4*)&T2H[i32][8];
      uint4 t3 = *(const uint4*)&T2H[i32][12];
      float acc[4];
      #pragma unroll
      for (int c = 0; c < 4; ++c) {
        uint4 a0 = *(const uint4*)&AmH[p][j4+c][0];
        uint4 a1 = *(const uint4*)&AmH[p][j4+c][4];
        uint4 a2 = *(const uint4*)&AmH[p][j4+c][8];
        uint4 a3 = *(const uint4*)&AmH[p][j4+c][12];
        acc[c] = dot8(t3,a3, dot8(t2,a2, dot8(t1,a1, dot8(t0,a0, 0.f))));
        if (i32 == j4 + c) acc[c] += 0.01f;
      }
      uint2 o; o.x = packh2(acc[0], acc[1]); o.y = packh2(acc[2], acc[3]);
      *(uint2*)&SgH[i32][g*2] = o;
    }
    if (tid >= 128 && tid < 128 + DZ) {
      int q = tid - 128;
      uint4 a0 = *(const uint4*)&AmH[p][q][0];
      uint4 a1 = *(const uint4*)&AmH[p][q][4];
      uint4 a2 = *(const uint4*)&AmH[p][q][8];
      uint4 a3 = *(const uint4*)&AmH[p][q][12];
      const float4* mp = (const float4*)munF;
      float4 n0 = mp[0], n1 = mp[1], n2 = mp[2], n3 = mp[3];
      float4 n4 = mp[4], n5 = mp[5], n6 = mp[6], n7 = mp[7];
      float m = 0.f;
      m = dot8f(a0, n0, n1, m);
      m = dot8f(a1, n2, n3, m);
      m = dot8f(a2, n4, n5, m);
      m = dot8f(a3, n6, n7, m);
      muvF[q] = m;
    }
    BAR();                                             // B7
  }
  #undef MIX_AND_PREFETCH
}

extern "C" void kernel_launch(void* const* d_in, const int* in_sizes, int n_in,
                              void* d_out, int out_size, void* d_ws, size_t ws_size,
                              hipStream_t stream) {
  const float* a    = (const float*)d_in[0];
  const float* A    = (const float*)d_in[1];
  const float* C    = (const float*)d_in[2];
  const float* a0   = (const float*)d_in[3];
  const float* Wih0 = (const float*)d_in[4];
  const float* Whh0 = (const float*)d_in[5];
  const float* bih0 = (const float*)d_in[6];
  const float* bhh0 = (const float*)d_in[7];
  const float* Wih1 = (const float*)d_in[8];
  const float* Whh1 = (const float*)d_in[9];
  const float* bih1 = (const float*)d_in[10];
  const float* bhh1 = (const float*)d_in[11];
  const float* Wlin = (const float*)d_in[12];
  const float* blin = (const float*)d_in[13];
  uint32_t* ws = (uint32_t*)d_ws;
  float* alpha = (float*)(ws + 103424);
  float* out = (float*)d_out;

  prep_kernel<<<404, 256, 0, stream>>>(Wih0, Whh0, bih0, bhh0, Wih1, Whh1, bih1, bhh1, ws);
  lstm_kernel<<<256, 512, 0, stream>>>(a, a0, ws, Wlin, blin, alpha);
  kalman_kernel<<<512, 256, 0, stream>>>(a, A, C, alpha, out);
}